// Round 4
// baseline (574.374 us; speedup 1.0000x reference)
//
#include <hip/hip_runtime.h>

typedef _Float16 f16;
typedef _Float16 f16x8 __attribute__((ext_vector_type(8)));
typedef _Float16 f16x4 __attribute__((ext_vector_type(4)));
typedef float f32x4 __attribute__((ext_vector_type(4)));

__device__ __forceinline__ void gld16(const void* g, void* l) {
    __builtin_amdgcn_global_load_lds(
        (const __attribute__((address_space(1))) void*)g,
        (__attribute__((address_space(3))) void*)l,
        16, 0, 0);
}

// ---------------- fp32 -> fp16 convert (vectorized) ----------------
__global__ __launch_bounds__(256) void f32_to_f16_vec(const float* __restrict__ in,
                                                      f16* __restrict__ out, long n4) {
    long i = (long)blockIdx.x * 256 + threadIdx.x;
    if (i < n4) {
        float4 v = ((const float4*)in)[i];
        f16x4 o = {(f16)v.x, (f16)v.y, (f16)v.z, (f16)v.w};
        ((f16x4*)out)[i] = o;
    }
}

// ---------------- gemm8: C[M,N] = A[M,K] * B[N,K]^T + bias ----------------
// m201-faithful port at MFMA-dominant pipe ratio: BM=512 BN=128 BK=32,
// 512 thr / 8 waves (4Mx2N), wave tile 128x64 (12 ds_read_b128 -> 32 MFMA).
// 3-deep LDS pipeline (3 x 40 KiB = 120 KiB, 1 blk/CU). Per K-step two
// dual-barrier phases: {reads | stage | bar | lgkm0 | setprio + 16 MFMA | bar};
// boundary s_waitcnt vmcnt(5) (counted, never 0 until drain).
constexpr int BUFE = 20480;  // elems per buffer: A 512x32 @0, B 128x32 @16384

template<int BUF, bool STG>
__device__ __forceinline__ void kstep(f16* sm,
                                      const f16*& gA, const f16*& gB, long k16,
                                      int dA, int dB, int rA, int rB,
                                      f32x4 (&acc)[8][4]) {
    const f16* bp = sm + BUF * BUFE;
    f16* tb = sm + ((BUF + 2) % 3) * BUFE;  // staging target: K-step t+2
    // ---- phase A: B-frags + A-frags(lo) | stage 3 | bar | lgkm0 | 16 MFMA | bar
    f16x8 bf[4], af[4];
#pragma unroll
    for (int nt = 0; nt < 4; ++nt) bf[nt] = *(const f16x8*)(bp + rB + nt * 512);
#pragma unroll
    for (int mt = 0; mt < 4; ++mt) af[mt] = *(const f16x8*)(bp + rA + mt * 512);
    if (STG) {
        gld16(gA,       tb + dA);
        gld16(gA + k16, tb + dA + 512);
        gld16(gB,       tb + 16384 + dB);
    }
    __builtin_amdgcn_s_barrier();
    asm volatile("s_waitcnt lgkmcnt(0)" ::: "memory");
    __builtin_amdgcn_sched_barrier(0);
    __builtin_amdgcn_s_setprio(1);
#pragma unroll
    for (int mt = 0; mt < 4; ++mt)
#pragma unroll
        for (int nt = 0; nt < 4; ++nt)
            acc[mt][nt] = __builtin_amdgcn_mfma_f32_16x16x32_f16(
                af[mt], bf[nt], acc[mt][nt], 0, 0, 0);
    __builtin_amdgcn_s_setprio(0);
    __builtin_amdgcn_s_barrier();
    // ---- phase B: A-frags(hi) | stage 2 | bar | lgkm0 | 16 MFMA | (caller VMB)
    f16x8 ah[4];
#pragma unroll
    for (int mt = 0; mt < 4; ++mt) ah[mt] = *(const f16x8*)(bp + rA + 2048 + mt * 512);
    if (STG) {
        gld16(gA + 2 * k16, tb + dA + 1024);
        gld16(gA + 3 * k16, tb + dA + 1536);
        gA += 32; gB += 32;
    }
    __builtin_amdgcn_s_barrier();
    asm volatile("s_waitcnt lgkmcnt(0)" ::: "memory");
    __builtin_amdgcn_sched_barrier(0);
    __builtin_amdgcn_s_setprio(1);
#pragma unroll
    for (int mt = 0; mt < 4; ++mt)
#pragma unroll
        for (int nt = 0; nt < 4; ++nt)
            acc[4 + mt][nt] = __builtin_amdgcn_mfma_f32_16x16x32_f16(
                ah[mt], bf[nt], acc[4 + mt][nt], 0, 0, 0);
    __builtin_amdgcn_s_setprio(0);
}

__global__ __launch_bounds__(512) void gemm8(const f16* __restrict__ A,
                                             const f16* __restrict__ B,
                                             const float* __restrict__ bias,
                                             float* __restrict__ Cf,
                                             f16* __restrict__ Ch,
                                             int M, int N, int K) {
    __shared__ f16 sm[3 * BUFE];  // 120 KiB -> 1 block/CU, 8 waves
    const int tid = threadIdx.x;
    const int w = tid >> 6, lane = tid & 63;
    const int quad = lane >> 4, l16 = lane & 15;
    const int wm = w >> 1, wn = w & 1;

    // XCD-banded swizzle: each XCD owns mpx private 512-row M-bands, sweeps N.
    const int nnb = N >> 7;
    const int mpx = (M >> 9) >> 3;
    const int xcd = blockIdx.x & 7;
    const int s = blockIdx.x >> 3;
    const int mband = s / nnb;
    const int nblk = s - mband * nnb;
    const long m0 = (long)(xcd * mpx + mband) << 9;
    const long n0 = (long)nblk << 7;

    // staging source: per-lane pre-swizzled col slot (inverse of read swizzle)
    const int r4 = lane >> 2;
    const int scw = ((lane & 3) ^ ((lane >> 3) & 3)) << 3;
    const f16* gA = A + (m0 + w * 64 + r4) * (long)K + scw;
    const f16* gB = B + (n0 + w * 16 + r4) * (long)K + scw;
    const long k16 = (long)16 * K;
    const int dA = __builtin_amdgcn_readfirstlane(w * 2048);
    const int dB = __builtin_amdgcn_readfirstlane(w * 512);

    // read-side swizzled fragment offsets: slot' = quad ^ ((row>>1)&3)
    const int swz8 = (quad ^ ((l16 >> 1) & 3)) << 3;
    const int rA = (wm * 128 + l16) * 32 + swz8;
    const int rB = 16384 + (wn * 64 + l16) * 32 + swz8;

    f32x4 acc[8][4] = {};

    // prologue: stage K-steps 0,1 (10 glds/wave); wait for step 0's 5 only
#pragma unroll
    for (int tt = 0; tt < 2; ++tt) {
        f16* d = sm + tt * BUFE;
        gld16(gA,           d + dA);
        gld16(gA + k16,     d + dA + 512);
        gld16(gA + 2 * k16, d + dA + 1024);
        gld16(gA + 3 * k16, d + dA + 1536);
        gld16(gB,           d + 16384 + dB);
        gA += 32; gB += 32;
    }
    asm volatile("s_waitcnt vmcnt(5)" ::: "memory");
    __builtin_amdgcn_s_barrier();

#define VMB(N) asm volatile("s_waitcnt vmcnt(" #N ")" ::: "memory"); \
               __builtin_amdgcn_s_barrier();

    // K = 1152 -> 36 K-steps; t=0..33 stage t+2; drain 5 -> 0
#pragma unroll 1
    for (int it = 0; it < 11; ++it) {
        kstep<0, true>(sm, gA, gB, k16, dA, dB, rA, rB, acc); VMB(5)
        kstep<1, true>(sm, gA, gB, k16, dA, dB, rA, rB, acc); VMB(5)
        kstep<2, true>(sm, gA, gB, k16, dA, dB, rA, rB, acc); VMB(5)
    }
    kstep<0, true >(sm, gA, gB, k16, dA, dB, rA, rB, acc); VMB(5)  // t=33 stages t=35
    kstep<1, false>(sm, gA, gB, k16, dA, dB, rA, rB, acc); VMB(0)  // t=34
    kstep<2, false>(sm, gA, gB, k16, dA, dB, rA, rB, acc);         // t=35
#undef VMB

    // epilogue (same verified C/D mapping)
    float bv[4];
#pragma unroll
    for (int nt = 0; nt < 4; ++nt)
        bv[nt] = bias ? bias[n0 + wn * 64 + nt * 16 + l16] : 0.f;
#pragma unroll
    for (int mt = 0; mt < 8; ++mt) {
#pragma unroll
        for (int r = 0; r < 4; ++r) {
            const long row = m0 + wm * 128 + mt * 16 + quad * 4 + r;
#pragma unroll
            for (int nt = 0; nt < 4; ++nt) {
                const long col = n0 + wn * 64 + nt * 16 + l16;
                const float v = acc[mt][nt][r] + bv[nt];
                if (Ch) Ch[row * (long)N + col] = (f16)v;
                else    Cf[row * (long)N + col] = v;
            }
        }
    }
}

// ---------------- RMSNorm q in-place (x attn scale) + k repacked to kc[bh][s][72] ----------------
__global__ __launch_bounds__(256) void qk_norm2(f16* __restrict__ qkv,
                                                const float* __restrict__ qg,
                                                const float* __restrict__ kg,
                                                f16* __restrict__ kc) {
    const float QSCALE = 0.117851130198f;  // 1/sqrt(72), folded into q
    const int t = blockIdx.x * 256 + threadIdx.x;  // 0..262143
    const int h = t & 15;
    const long bs = t >> 4;
    f16* qp = qkv + bs * 3456 + h * 72;
    {
        f16x8 v[9];
        float ss = 0.f;
#pragma unroll
        for (int c = 0; c < 9; ++c) {
            v[c] = *(const f16x8*)(qp + c * 8);
#pragma unroll
            for (int j = 0; j < 8; ++j) { float f = (float)v[c][j]; ss += f * f; }
        }
        const float rs = rsqrtf(ss * (1.f / 72.f) + 1.1920928955078125e-7f) * QSCALE;
#pragma unroll
        for (int c = 0; c < 9; ++c) {
            f16x8 o;
#pragma unroll
            for (int j = 0; j < 8; ++j) o[j] = (f16)((float)v[c][j] * rs * qg[c * 8 + j]);
            *(f16x8*)(qp + c * 8) = o;
        }
    }
    {
        const f16* kp = qp + 1152;
        f16* dst = kc + ((long)((bs >> 10) * 16 + h) * 1024 + (bs & 1023)) * 72;
        f16x8 v[9];
        float ss = 0.f;
#pragma unroll
        for (int c = 0; c < 9; ++c) {
            v[c] = *(const f16x8*)(kp + c * 8);
#pragma unroll
            for (int j = 0; j < 8; ++j) { float f = (float)v[c][j]; ss += f * f; }
        }
        const float rs = rsqrtf(ss * (1.f / 72.f) + 1.1920928955078125e-7f);
#pragma unroll
        for (int c = 0; c < 9; ++c) {
            f16x8 o;
#pragma unroll
            for (int j = 0; j < 8; ++j) o[j] = (f16)((float)v[c][j] * rs * kg[c * 8 + j]);
            *(f16x8*)(dst + c * 8) = o;
        }
    }
}

// ---------------- V transpose: qkv[b,s,2304+h*72+d] -> Vt[bh][72][1024] ----------------
__global__ __launch_bounds__(256) void vt_kernel(const f16* __restrict__ QKV,
                                                 f16* __restrict__ Vt) {
    __shared__ f16 tile[64][73];
    const int tid = threadIdx.x;
    const int bh = blockIdx.x;
    const int b = bh >> 4, h = bh & 15;
    const int s0 = blockIdx.y * 64;
    for (int idx = tid; idx < 64 * 72; idx += 256) {
        const int r = idx / 72, c = idx % 72;
        tile[r][c] = QKV[((long)(b * 1024 + s0 + r)) * 3456 + 2304 + h * 72 + c];
    }
    __syncthreads();
    for (int idx = tid; idx < 72 * 64; idx += 256) {
        const int d = idx >> 6, s = idx & 63;
        Vt[((long)bh * 72 + d) * 1024 + s0 + s] = tile[s][d];
    }
}

// ---------------- Flash attention v2 ----------------
__global__ __launch_bounds__(256) void attn2(const f16* __restrict__ QKV,
                                             const f16* __restrict__ Kc,
                                             const f16* __restrict__ Vt,
                                             f16* __restrict__ O) {
    constexpr int S = 1024;
    __shared__ f16 smem[64 * 72 + 80 * 76];  // Ks | Vs(padded), 21376 B
    f16* Ks = smem;
    f16* Vs = smem + 64 * 72;
    const int tid = threadIdx.x;
    const int w = tid >> 6, lane = tid & 63;
    const int quad = lane >> 4, l16 = lane & 15;

    // XCD swizzle: qt fastest within a bh, bh group-of-8 per XCD
    const int b = blockIdx.x;
    const int xcd = b & 7;
    const int j = b >> 3;
    const int bh = ((j >> 3) << 3) | xcd;
    const int qt = j & 7;
    const int bb = bh >> 4, h = bh & 15;
    const int q0 = qt * 128;

    // pad rows of Vs: row 72 = ones (l-accumulator), rows 73..79 = 0
    for (int i = tid; i < 8 * 76; i += 256) {
        const int pr = i / 76, pc = i % 76;
        Vs[(72 + pr) * 76 + pc] = (pr == 0 && pc < 64) ? (f16)1.f : (f16)0.f;
    }

    // Q fragments (q pre-scaled by 1/sqrt(72) in qk_norm2); chunk2 zero-padded
    const f16* qrow0 = QKV + ((long)(bb * 1024 + q0 + w * 32 + l16)) * 3456 + h * 72;
    const f16* qrow1 = qrow0 + (long)16 * 3456;
    f16x8 qz = {};
    f16x8 qf[2][3];
    qf[0][0] = *(const f16x8*)(qrow0 + quad * 8);
    qf[0][1] = *(const f16x8*)(qrow0 + 32 + quad * 8);
    qf[0][2] = (quad == 0) ? *(const f16x8*)(qrow0 + 64) : qz;
    qf[1][0] = *(const f16x8*)(qrow1 + quad * 8);
    qf[1][1] = *(const f16x8*)(qrow1 + 32 + quad * 8);
    qf[1][2] = (quad == 0) ? *(const f16x8*)(qrow1 + 64) : qz;

    f32x4 o[2][5] = {};

    const f16* gK = Kc + (long)bh * S * 72;
    const f16* gV = Vt + (long)bh * 72 * S;

    for (int s0 = 0; s0 < S; s0 += 64) {
        for (int ch = w; ch < 9; ch += 4)
            gld16(gK + (long)s0 * 72 + ch * 512 + lane * 8,
                  &Ks[__builtin_amdgcn_readfirstlane(ch * 512)]);
#pragma unroll
        for (int it = 0; it < 3; ++it) {
            const int idx = it * 256 + tid;
            if (idx < 576) {
                const int d = idx >> 3, s8 = (idx & 7) * 8;
                f16x8 v = *(const f16x8*)(gV + (long)d * 1024 + s0 + s8);
                f16x4 lo = {v[0], v[1], v[2], v[3]};
                f16x4 hi = {v[4], v[5], v[6], v[7]};
                *(f16x4*)&Vs[d * 76 + s8] = lo;
                *(f16x4*)&Vs[d * 76 + s8 + 4] = hi;
            }
        }
        __syncthreads();

        // Sc^T[s][q] = K·Q^T : A=K-frag, B=Q-frag
        f32x4 sc[4][2] = {};
#pragma unroll
        for (int ss = 0; ss < 4; ++ss) {
            const int base = (ss * 16 + l16) * 72;
            f16x8 k0 = *(const f16x8*)&Ks[base + quad * 8];
            f16x8 k1 = *(const f16x8*)&Ks[base + 32 + quad * 8];
            f16x8 k2 = *(const f16x8*)&Ks[base + 64 + quad * 8];  // junk for quad>0: q-frag is 0
            sc[ss][0] = __builtin_amdgcn_mfma_f32_16x16x32_f16(k0, qf[0][0], sc[ss][0], 0, 0, 0);
            sc[ss][0] = __builtin_amdgcn_mfma_f32_16x16x32_f16(k1, qf[0][1], sc[ss][0], 0, 0, 0);
            sc[ss][0] = __builtin_amdgcn_mfma_f32_16x16x32_f16(k2, qf[0][2], sc[ss][0], 0, 0, 0);
            sc[ss][1] = __builtin_amdgcn_mfma_f32_16x16x32_f16(k0, qf[1][0], sc[ss][1], 0, 0, 0);
            sc[ss][1] = __builtin_amdgcn_mfma_f32_16x16x32_f16(k1, qf[1][1], sc[ss][1], 0, 0, 0);
            sc[ss][1] = __builtin_amdgcn_mfma_f32_16x16x32_f16(k2, qf[1][2], sc[ss][1], 0, 0, 0);
        }

        // p = exp(s) — no max subtraction: |s| <= sqrt(72) ~ 8.5, exp <= ~4900
        f16x4 pf[4][2];
#pragma unroll
        for (int ss = 0; ss < 4; ++ss)
#pragma unroll
            for (int qs = 0; qs < 2; ++qs) {
                f16x4 pk;
#pragma unroll
                for (int r = 0; r < 4; ++r) pk[r] = (f16)__expf(sc[ss][qs][r]);
                pf[ss][qs] = pk;
            }

        // O^T[d][q] += Vt_frag · P^T   (16x16x16, K = s)
#pragma unroll
        for (int vt = 0; vt < 5; ++vt) {
#pragma unroll
            for (int ss = 0; ss < 4; ++ss) {
                f16x4 vf = *(const f16x4*)&Vs[(vt * 16 + l16) * 76 + ss * 16 + quad * 4];
                o[0][vt] = __builtin_amdgcn_mfma_f32_16x16x16f16(vf, pf[ss][0], o[0][vt], 0, 0, 0);
                o[1][vt] = __builtin_amdgcn_mfma_f32_16x16x16f16(vf, pf[ss][1], o[1][vt], 0, 0, 0);
            }
        }
        __syncthreads();
    }

    // l lives at d==72 -> (vt=4, quad=2, r=0); broadcast per q column
    const float l0 = __shfl(o[0][4][0], 32 + l16);
    const float l1 = __shfl(o[1][4][0], 32 + l16);
    const float inv[2] = {1.f / l0, 1.f / l1};

    // transpose O^T -> O via per-wave LDS scratch (rows of 80), then coalesced stores
    f16* es = smem + w * 2560;  // 32 rows x 80
#pragma unroll
    for (int qs = 0; qs < 2; ++qs) {
        f16* row = es + (qs * 16 + l16) * 80;
#pragma unroll
        for (int vt = 0; vt < 5; ++vt)
#pragma unroll
            for (int r = 0; r < 4; ++r) {
                const int d = vt * 16 + quad * 4 + r;
                if (d < 72) row[d] = (f16)(o[qs][vt][r] * inv[qs]);
            }
    }
    const long rowbase = (long)bb * 1024 + q0 + w * 32;
#pragma unroll
    for (int it = 0; it < 5; ++it) {
        const int idx = it * 64 + lane;
        if (idx < 288) {
            const int q = idx / 9, c = idx - q * 9;
            f16x4 a = *(const f16x4*)&es[q * 80 + c * 8];
            f16x4 b2 = *(const f16x4*)&es[q * 80 + c * 8 + 4];
            f16* dst = O + (rowbase + q) * 1152 + h * 72 + c * 8;
            *(f16x4*)dst = a;
            *(f16x4*)(dst + 4) = b2;
        }
    }
}

extern "C" void kernel_launch(void* const* d_in, const int* in_sizes, int n_in,
                              void* d_out, int out_size, void* d_ws, size_t ws_size,
                              hipStream_t stream) {
    const float* x       = (const float*)d_in[0];
    const float* w_qkv   = (const float*)d_in[1];
    const float* b_qkv   = (const float*)d_in[2];
    const float* q_gamma = (const float*)d_in[3];
    const float* k_gamma = (const float*)d_in[4];
    const float* w_proj  = (const float*)d_in[5];
    const float* b_proj  = (const float*)d_in[6];
    float* out = (float*)d_out;

    char* p = (char*)d_ws;
    f16* x_h = (f16*)p;      p += (size_t)16384 * 1152 * 2;  // reused as ao after QKV GEMM
    f16* wqkv_h = (f16*)p;   p += (size_t)3456 * 1152 * 2;
    f16* wproj_h = (f16*)p;  p += (size_t)1152 * 1152 * 2;
    f16* qkv_h = (f16*)p;    p += (size_t)16384 * 3456 * 2;
    const size_t needed = (size_t)(p - (char*)d_ws);
    if (ws_size < needed) return;

    // d_out doubles as scratch until the final proj GEMM overwrites it:
    f16* k_c = (f16*)d_out;                        // [256][1024][72]
    f16* v_t = (f16*)d_out + (size_t)16384 * 1152; // [256][72][1024]

    f32_to_f16_vec<<<18432, 256, 0, stream>>>(x, x_h, 16384L * 1152 / 4);
    f32_to_f16_vec<<<3888, 256, 0, stream>>>(w_qkv, wqkv_h, 3456L * 1152 / 4);
    f32_to_f16_vec<<<1296, 256, 0, stream>>>(w_proj, wproj_h, 1152L * 1152 / 4);

    // QKV GEMM: M=16384, N=3456, K=1152 -> 32 x 27 blocks of 512x128
    gemm8<<<864, 512, 0, stream>>>(
        x_h, wqkv_h, b_qkv, nullptr, qkv_h, 16384, 3456, 1152);

    qk_norm2<<<1024, 256, 0, stream>>>(qkv_h, q_gamma, k_gamma, k_c);
    vt_kernel<<<dim3(256, 16), 256, 0, stream>>>(qkv_h, v_t);

    attn2<<<2048, 256, 0, stream>>>(qkv_h, k_c, v_t, x_h /* ao */);

    // proj GEMM: M=16384, N=1152, K=1152 -> 32 x 9 blocks of 512x128
    gemm8<<<288, 512, 0, stream>>>(
        x_h, wproj_h, b_proj, out, nullptr, 16384, 1152, 1152);
}

// Round 5
// 516.172 us; speedup vs baseline: 1.1128x; 1.1128x over previous
//
#include <hip/hip_runtime.h>

typedef _Float16 f16;
typedef _Float16 f16x8 __attribute__((ext_vector_type(8)));
typedef _Float16 f16x4 __attribute__((ext_vector_type(4)));
typedef float f32x4 __attribute__((ext_vector_type(4)));

__device__ __forceinline__ void gld16(const void* g, void* l) {
    __builtin_amdgcn_global_load_lds(
        (const __attribute__((address_space(1))) void*)g,
        (__attribute__((address_space(3))) void*)l,
        16, 0, 0);
}

// ---------------- fp32 -> fp16 convert (vectorized) ----------------
__global__ __launch_bounds__(256) void f32_to_f16_vec(const float* __restrict__ in,
                                                      f16* __restrict__ out, long n4) {
    long i = (long)blockIdx.x * 256 + threadIdx.x;
    if (i < n4) {
        float4 v = ((const float4*)in)[i];
        f16x4 o = {(f16)v.x, (f16)v.y, (f16)v.z, (f16)v.w};
        ((f16x4*)out)[i] = o;
    }
}

// ---------------- gemm8: C[M,N] = A[M,K] * B[N,K]^T + bias ----------------
// R2 config (best measured: 153.7 us QKV, MfmaUtil 38, 0 conflicts).
// 256x128 tile, BK=32, 4 waves (2x2) each owning 128x64. 3-deep LDS pipeline
// (72 KiB -> 2 blocks/CU), one barrier + one counted vmcnt(6) per K-tile.
constexpr int GEMM_BUF_E = 12288;  // f16 elems per buffer: A 256x32 | B 128x32

struct GPtrs {
    const f16 *a0, *a1, *a2, *a3, *b0, *b1;
};

__device__ __forceinline__ void stage6(f16* s, const GPtrs& g, int dA, int dB) {
    gld16(g.a0, s + dA);
    gld16(g.a1, s + dA + 2048);
    gld16(g.a2, s + dA + 4096);
    gld16(g.a3, s + dA + 6144);
    gld16(g.b0, s + dB);
    gld16(g.b1, s + dB + 2048);
}

template<int BUF, bool STG>
__device__ __forceinline__ void tile_step(f16* sm, GPtrs& g,
                                          int dA, int dB,
                                          int offA, int offB,
                                          f32x4 (&acc)[8][4]) {
    const f16* bp = sm + BUF * GEMM_BUF_E;
    if (STG) {
        constexpr int SB = (BUF + 2) % 3;
        stage6(sm + SB * GEMM_BUF_E, g, dA, dB);
        g.a0 += 32; g.a1 += 32; g.a2 += 32; g.a3 += 32;
        g.b0 += 32; g.b1 += 32;
    }
    f16x8 bf[4], af[4], ag[4];
#pragma unroll
    for (int nt = 0; nt < 4; ++nt) bf[nt] = *(const f16x8*)(bp + offB + nt * 512);
#pragma unroll
    for (int mt = 0; mt < 4; ++mt) af[mt] = *(const f16x8*)(bp + offA + mt * 512);
#pragma unroll
    for (int mt = 0; mt < 4; ++mt) ag[mt] = *(const f16x8*)(bp + offA + 2048 + mt * 512);
    __builtin_amdgcn_s_setprio(1);
#pragma unroll
    for (int mt = 0; mt < 4; ++mt)
#pragma unroll
        for (int nt = 0; nt < 4; ++nt)
            acc[mt][nt] = __builtin_amdgcn_mfma_f32_16x16x32_f16(
                af[mt], bf[nt], acc[mt][nt], 0, 0, 0);
#pragma unroll
    for (int mt = 0; mt < 4; ++mt)
#pragma unroll
        for (int nt = 0; nt < 4; ++nt)
            acc[4 + mt][nt] = __builtin_amdgcn_mfma_f32_16x16x32_f16(
                ag[mt], bf[nt], acc[4 + mt][nt], 0, 0, 0);
    __builtin_amdgcn_s_setprio(0);
}

__global__ __launch_bounds__(256, 2) void gemm8(const f16* __restrict__ A,
                                                const f16* __restrict__ B,
                                                const float* __restrict__ bias,
                                                float* __restrict__ Cf,
                                                f16* __restrict__ Ch,
                                                int M, int N, int K) {
    __shared__ f16 sm[3 * GEMM_BUF_E];  // 72 KiB -> 2 blocks/CU
    const int tid = threadIdx.x;
    const int w = tid >> 6, lane = tid & 63;
    const int quad = lane >> 4, l16 = lane & 15;
    const int wm = w >> 1, wn = w & 1;

    // XCD-banded swizzle: each XCD owns mpx private 256-row M-bands, sweeps N.
    const int nnb = N >> 7;
    const int mpx = (M >> 8) >> 3;
    const int xcd = blockIdx.x & 7;
    const int s = blockIdx.x >> 3;
    const int mband = s / nnb;
    const int nblk = s - mband * nnb;
    const long m0 = (long)(xcd * mpx + mband) << 8;
    const long n0 = (long)nblk << 7;

    // staging source: per-lane pre-swizzled column slot (inverse of read swz)
    const int r4 = lane >> 2;                              // row within 64-chunk
    const int sc = ((lane & 3) ^ ((lane >> 3) & 3)) << 3;  // f16 col
    GPtrs g;
    g.a0 = A + (m0 +   0 + w * 16 + r4) * (long)K + sc;
    g.a1 = A + (m0 +  64 + w * 16 + r4) * (long)K + sc;
    g.a2 = A + (m0 + 128 + w * 16 + r4) * (long)K + sc;
    g.a3 = A + (m0 + 192 + w * 16 + r4) * (long)K + sc;
    g.b0 = B + (n0 +   0 + w * 16 + r4) * (long)K + sc;
    g.b1 = B + (n0 +  64 + w * 16 + r4) * (long)K + sc;
    // staging dest (wave-uniform, linear)
    const int dA = __builtin_amdgcn_readfirstlane(w * 512);
    const int dB = __builtin_amdgcn_readfirstlane(8192 + w * 512);

    // compute-side swizzled fragment offsets (elems)
    const int swz = (quad ^ ((l16 >> 1) & 3)) << 3;
    const int offA = (wm * 128 + l16) * 32 + swz;
    const int offB = 8192 + (wn * 64 + l16) * 32 + swz;

    f32x4 acc[8][4] = {};

    // prologue: stage tiles 0,1 (12 glds/wave); wait for tile 0 only
    stage6(sm, g, dA, dB);
    {
        GPtrs g1 = g;
        g1.a0 += 32; g1.a1 += 32; g1.a2 += 32; g1.a3 += 32; g1.b0 += 32; g1.b1 += 32;
        stage6(sm + GEMM_BUF_E, g1, dA, dB);
    }
    g.a0 += 64; g.a1 += 64; g.a2 += 64; g.a3 += 64; g.b0 += 64; g.b1 += 64;
    asm volatile("s_waitcnt vmcnt(6)" ::: "memory");
    __builtin_amdgcn_s_barrier();
    __builtin_amdgcn_sched_barrier(0);

#define VMB(NSTR) asm volatile("s_waitcnt vmcnt(" NSTR ")" ::: "memory"); \
                  __builtin_amdgcn_s_barrier();                           \
                  __builtin_amdgcn_sched_barrier(0);

    // main loop: 36 K-tiles; during tile t stage t+2 into buffer (t+2)%3.
#pragma unroll 1
    for (int it = 0; it < 11; ++it) {
        tile_step<0, true>(sm, g, dA, dB, offA, offB, acc); VMB("6")
        tile_step<1, true>(sm, g, dA, dB, offA, offB, acc); VMB("6")
        tile_step<2, true>(sm, g, dA, dB, offA, offB, acc); VMB("6")
    }
    tile_step<0, true >(sm, g, dA, dB, offA, offB, acc); VMB("6")   // t=33 stages t=35
    tile_step<1, false>(sm, g, dA, dB, offA, offB, acc); VMB("0")   // t=34
    tile_step<2, false>(sm, g, dA, dB, offA, offB, acc);            // t=35
#undef VMB

    // epilogue (same verified C/D mapping)
    float bv[4];
#pragma unroll
    for (int nt = 0; nt < 4; ++nt)
        bv[nt] = bias ? bias[n0 + wn * 64 + nt * 16 + l16] : 0.f;
#pragma unroll
    for (int mt = 0; mt < 8; ++mt) {
#pragma unroll
        for (int r = 0; r < 4; ++r) {
            const long row = m0 + wm * 128 + mt * 16 + quad * 4 + r;
#pragma unroll
            for (int nt = 0; nt < 4; ++nt) {
                const long col = n0 + wn * 64 + nt * 16 + l16;
                const float v = acc[mt][nt][r] + bv[nt];
                if (Ch) Ch[row * (long)N + col] = (f16)v;
                else    Cf[row * (long)N + col] = v;
            }
        }
    }
}

// ---------------- RMSNorm q in-place (x attn scale) + k repacked to kc[bh][s][72] ----------------
__global__ __launch_bounds__(256) void qk_norm2(f16* __restrict__ qkv,
                                                const float* __restrict__ qg,
                                                const float* __restrict__ kg,
                                                f16* __restrict__ kc) {
    const float QSCALE = 0.117851130198f;  // 1/sqrt(72), folded into q
    const int t = blockIdx.x * 256 + threadIdx.x;  // 0..262143
    const int h = t & 15;
    const long bs = t >> 4;
    f16* qp = qkv + bs * 3456 + h * 72;
    {
        f16x8 v[9];
        float ss = 0.f;
#pragma unroll
        for (int c = 0; c < 9; ++c) {
            v[c] = *(const f16x8*)(qp + c * 8);
#pragma unroll
            for (int j = 0; j < 8; ++j) { float f = (float)v[c][j]; ss += f * f; }
        }
        const float rs = rsqrtf(ss * (1.f / 72.f) + 1.1920928955078125e-7f) * QSCALE;
#pragma unroll
        for (int c = 0; c < 9; ++c) {
            f16x8 o;
#pragma unroll
            for (int j = 0; j < 8; ++j) o[j] = (f16)((float)v[c][j] * rs * qg[c * 8 + j]);
            *(f16x8*)(qp + c * 8) = o;
        }
    }
    {
        const f16* kp = qp + 1152;
        f16* dst = kc + ((long)((bs >> 10) * 16 + h) * 1024 + (bs & 1023)) * 72;
        f16x8 v[9];
        float ss = 0.f;
#pragma unroll
        for (int c = 0; c < 9; ++c) {
            v[c] = *(const f16x8*)(kp + c * 8);
#pragma unroll
            for (int j = 0; j < 8; ++j) { float f = (float)v[c][j]; ss += f * f; }
        }
        const float rs = rsqrtf(ss * (1.f / 72.f) + 1.1920928955078125e-7f);
#pragma unroll
        for (int c = 0; c < 9; ++c) {
            f16x8 o;
#pragma unroll
            for (int j = 0; j < 8; ++j) o[j] = (f16)((float)v[c][j] * rs * kg[c * 8 + j]);
            *(f16x8*)(dst + c * 8) = o;
        }
    }
}

// ---------------- V transpose: qkv[b,s,2304+h*72+d] -> Vt[bh][72][1024] ----------------
__global__ __launch_bounds__(256) void vt_kernel(const f16* __restrict__ QKV,
                                                 f16* __restrict__ Vt) {
    __shared__ f16 tile[64][73];
    const int tid = threadIdx.x;
    const int bh = blockIdx.x;
    const int b = bh >> 4, h = bh & 15;
    const int s0 = blockIdx.y * 64;
    for (int idx = tid; idx < 64 * 72; idx += 256) {
        const int r = idx / 72, c = idx % 72;
        tile[r][c] = QKV[((long)(b * 1024 + s0 + r)) * 3456 + 2304 + h * 72 + c];
    }
    __syncthreads();
    for (int idx = tid; idx < 72 * 64; idx += 256) {
        const int d = idx >> 6, s = idx & 63;
        Vt[((long)bh * 72 + d) * 1024 + s0 + s] = tile[s][d];
    }
}

// ---------------- Flash attention v3: double-buffered K/V, async staging ----------------
// Per S-tile t: issue K gld16(t+1) + V global->reg loads(t+1) BEFORE compute(t);
// after PV, write V regs -> LDS(buf^1); ONE __syncthreads per iter (was 2).
// Staging latency (L2 ~200cy) hides under ~2000cy of QK/exp/PV compute.
__global__ __launch_bounds__(256) void attn2(const f16* __restrict__ QKV,
                                             const f16* __restrict__ Kc,
                                             const f16* __restrict__ Vt,
                                             f16* __restrict__ O) {
    constexpr int S = 1024;
    constexpr int KSZ = 64 * 72;   // 4608 elems per K buffer
    constexpr int VSZ = 80 * 76;   // 6080 elems per V buffer (padded rows)
    __shared__ f16 smem[2 * KSZ + 2 * VSZ];  // 42752 B -> 3 blocks/CU
    f16* KsA = smem;               // [2][KSZ]
    f16* VsA = smem + 2 * KSZ;     // [2][VSZ]
    const int tid = threadIdx.x;
    const int w = tid >> 6, lane = tid & 63;
    const int quad = lane >> 4, l16 = lane & 15;

    // XCD swizzle: qt fastest within a bh, bh group-of-8 per XCD
    const int b = blockIdx.x;
    const int xcd = b & 7;
    const int j = b >> 3;
    const int bh = ((j >> 3) << 3) | xcd;
    const int qt = j & 7;
    const int bb = bh >> 4, h = bh & 15;
    const int q0 = qt * 128;

    // pad rows of both Vs buffers: row 72 = ones (l-accumulator), 73..79 = 0
    for (int i = tid; i < 8 * 76; i += 256) {
        const int pr = i / 76, pc = i % 76;
        const f16 pv = (pr == 0 && pc < 64) ? (f16)1.f : (f16)0.f;
        VsA[(72 + pr) * 76 + pc] = pv;
        VsA[VSZ + (72 + pr) * 76 + pc] = pv;
    }

    // Q fragments (q pre-scaled by 1/sqrt(72) in qk_norm2); chunk2 zero-padded
    const f16* qrow0 = QKV + ((long)(bb * 1024 + q0 + w * 32 + l16)) * 3456 + h * 72;
    const f16* qrow1 = qrow0 + (long)16 * 3456;
    f16x8 qz = {};
    f16x8 qf[2][3];
    qf[0][0] = *(const f16x8*)(qrow0 + quad * 8);
    qf[0][1] = *(const f16x8*)(qrow0 + 32 + quad * 8);
    qf[0][2] = (quad == 0) ? *(const f16x8*)(qrow0 + 64) : qz;
    qf[1][0] = *(const f16x8*)(qrow1 + quad * 8);
    qf[1][1] = *(const f16x8*)(qrow1 + 32 + quad * 8);
    qf[1][2] = (quad == 0) ? *(const f16x8*)(qrow1 + 64) : qz;

    f32x4 o[2][5] = {};

    const f16* gK = Kc + (long)bh * S * 72;
    const f16* gV = Vt + (long)bh * 72 * S;

    f16x8 vr[3];  // V(t+1) in-flight registers

    // prologue: stage tile 0 into buffer 0
    for (int ch = w; ch < 9; ch += 4)
        gld16(gK + ch * 512 + lane * 8,
              &KsA[__builtin_amdgcn_readfirstlane(ch * 512)]);
#pragma unroll
    for (int it = 0; it < 3; ++it) {
        const int idx = it * 256 + tid;
        if (idx < 576)
            vr[it] = *(const f16x8*)(gV + (long)(idx >> 3) * 1024 + (idx & 7) * 8);
    }
#pragma unroll
    for (int it = 0; it < 3; ++it) {
        const int idx = it * 256 + tid;
        if (idx < 576) {
            const int d = idx >> 3, s8 = (idx & 7) * 8;
            f16x4 lo = {vr[it][0], vr[it][1], vr[it][2], vr[it][3]};
            f16x4 hi = {vr[it][4], vr[it][5], vr[it][6], vr[it][7]};
            *(f16x4*)&VsA[d * 76 + s8] = lo;
            *(f16x4*)&VsA[d * 76 + s8 + 4] = hi;
        }
    }
    __syncthreads();

#pragma unroll 1
    for (int t = 0; t < 16; ++t) {
        const int buf = t & 1;
        const f16* Ks = KsA + buf * KSZ;
        const f16* Vs = VsA + buf * VSZ;

        // issue next tile's staging before compute (latency hides under MFMA)
        if (t < 15) {
            const int s1 = (t + 1) * 64;
            for (int ch = w; ch < 9; ch += 4)
                gld16(gK + (long)s1 * 72 + ch * 512 + lane * 8,
                      &KsA[__builtin_amdgcn_readfirstlane((buf ^ 1) * KSZ + ch * 512)]);
#pragma unroll
            for (int it = 0; it < 3; ++it) {
                const int idx = it * 256 + tid;
                if (idx < 576)
                    vr[it] = *(const f16x8*)(gV + (long)(idx >> 3) * 1024 + s1 + (idx & 7) * 8);
            }
        }

        // Sc^T[s][q] = K·Q^T : A=K-frag, B=Q-frag
        f32x4 sc[4][2] = {};
        __builtin_amdgcn_s_setprio(1);
#pragma unroll
        for (int ss = 0; ss < 4; ++ss) {
            const int base = (ss * 16 + l16) * 72;
            f16x8 k0 = *(const f16x8*)&Ks[base + quad * 8];
            f16x8 k1 = *(const f16x8*)&Ks[base + 32 + quad * 8];
            f16x8 k2 = *(const f16x8*)&Ks[base + 64 + quad * 8];  // junk for quad>0: q-frag is 0
            sc[ss][0] = __builtin_amdgcn_mfma_f32_16x16x32_f16(k0, qf[0][0], sc[ss][0], 0, 0, 0);
            sc[ss][0] = __builtin_amdgcn_mfma_f32_16x16x32_f16(k1, qf[0][1], sc[ss][0], 0, 0, 0);
            sc[ss][0] = __builtin_amdgcn_mfma_f32_16x16x32_f16(k2, qf[0][2], sc[ss][0], 0, 0, 0);
            sc[ss][1] = __builtin_amdgcn_mfma_f32_16x16x32_f16(k0, qf[1][0], sc[ss][1], 0, 0, 0);
            sc[ss][1] = __builtin_amdgcn_mfma_f32_16x16x32_f16(k1, qf[1][1], sc[ss][1], 0, 0, 0);
            sc[ss][1] = __builtin_amdgcn_mfma_f32_16x16x32_f16(k2, qf[1][2], sc[ss][1], 0, 0, 0);
        }
        __builtin_amdgcn_s_setprio(0);

        // p = exp(s) — no max subtraction: |s| <= sqrt(72) ~ 8.5, exp <= ~4900
        f16x4 pf[4][2];
#pragma unroll
        for (int ss = 0; ss < 4; ++ss)
#pragma unroll
            for (int qs = 0; qs < 2; ++qs) {
                f16x4 pk;
#pragma unroll
                for (int r = 0; r < 4; ++r) pk[r] = (f16)__expf(sc[ss][qs][r]);
                pf[ss][qs] = pk;
            }

        // O^T[d][q] += Vt_frag · P^T   (16x16x16, K = s)
        __builtin_amdgcn_s_setprio(1);
#pragma unroll
        for (int vt = 0; vt < 5; ++vt) {
#pragma unroll
            for (int ss = 0; ss < 4; ++ss) {
                f16x4 vf = *(const f16x4*)&Vs[(vt * 16 + l16) * 76 + ss * 16 + quad * 4];
                o[0][vt] = __builtin_amdgcn_mfma_f32_16x16x16f16(vf, pf[ss][0], o[0][vt], 0, 0, 0);
                o[1][vt] = __builtin_amdgcn_mfma_f32_16x16x16f16(vf, pf[ss][1], o[1][vt], 0, 0, 0);
            }
        }
        __builtin_amdgcn_s_setprio(0);

        // land V(t+1) regs into the other buffer; barrier covers all hazards
        if (t < 15) {
#pragma unroll
            for (int it = 0; it < 3; ++it) {
                const int idx = it * 256 + tid;
                if (idx < 576) {
                    const int d = idx >> 3, s8 = (idx & 7) * 8;
                    f16x4 lo = {vr[it][0], vr[it][1], vr[it][2], vr[it][3]};
                    f16x4 hi = {vr[it][4], vr[it][5], vr[it][6], vr[it][7]};
                    *(f16x4*)&VsA[(buf ^ 1) * VSZ + d * 76 + s8] = lo;
                    *(f16x4*)&VsA[(buf ^ 1) * VSZ + d * 76 + s8 + 4] = hi;
                }
            }
        }
        __syncthreads();
    }

    // l lives at d==72 -> (vt=4, quad=2, r=0); broadcast per q column
    const float l0 = __shfl(o[0][4][0], 32 + l16);
    const float l1 = __shfl(o[1][4][0], 32 + l16);
    const float inv[2] = {1.f / l0, 1.f / l1};

    // transpose O^T -> O via per-wave LDS scratch (rows of 80), then coalesced stores
    f16* es = smem + w * 2560;  // 32 rows x 80
#pragma unroll
    for (int qs = 0; qs < 2; ++qs) {
        f16* row = es + (qs * 16 + l16) * 80;
#pragma unroll
        for (int vt = 0; vt < 5; ++vt)
#pragma unroll
            for (int r = 0; r < 4; ++r) {
                const int d = vt * 16 + quad * 4 + r;
                if (d < 72) row[d] = (f16)(o[qs][vt][r] * inv[qs]);
            }
    }
    const long rowbase = (long)bb * 1024 + q0 + w * 32;
#pragma unroll
    for (int it = 0; it < 5; ++it) {
        const int idx = it * 64 + lane;
        if (idx < 288) {
            const int q = idx / 9, c = idx - q * 9;
            f16x4 a = *(const f16x4*)&es[q * 80 + c * 8];
            f16x4 b2 = *(const f16x4*)&es[q * 80 + c * 8 + 4];
            f16* dst = O + (rowbase + q) * 1152 + h * 72 + c * 8;
            *(f16x4*)dst = a;
            *(f16x4*)(dst + 4) = b2;
        }
    }
}

extern "C" void kernel_launch(void* const* d_in, const int* in_sizes, int n_in,
                              void* d_out, int out_size, void* d_ws, size_t ws_size,
                              hipStream_t stream) {
    const float* x       = (const float*)d_in[0];
    const float* w_qkv   = (const float*)d_in[1];
    const float* b_qkv   = (const float*)d_in[2];
    const float* q_gamma = (const float*)d_in[3];
    const float* k_gamma = (const float*)d_in[4];
    const float* w_proj  = (const float*)d_in[5];
    const float* b_proj  = (const float*)d_in[6];
    float* out = (float*)d_out;

    char* p = (char*)d_ws;
    f16* x_h = (f16*)p;      p += (size_t)16384 * 1152 * 2;  // reused as ao after QKV GEMM
    f16* wqkv_h = (f16*)p;   p += (size_t)3456 * 1152 * 2;
    f16* wproj_h = (f16*)p;  p += (size_t)1152 * 1152 * 2;
    f16* qkv_h = (f16*)p;    p += (size_t)16384 * 3456 * 2;
    const size_t needed = (size_t)(p - (char*)d_ws);
    if (ws_size < needed) return;

    // d_out doubles as scratch until the final proj GEMM overwrites it:
    f16* k_c = (f16*)d_out;                        // [256][1024][72]
    f16* v_t = (f16*)d_out + (size_t)16384 * 1152; // [256][72][1024]

    f32_to_f16_vec<<<18432, 256, 0, stream>>>(x, x_h, 16384L * 1152 / 4);
    f32_to_f16_vec<<<3888, 256, 0, stream>>>(w_qkv, wqkv_h, 3456L * 1152 / 4);
    f32_to_f16_vec<<<1296, 256, 0, stream>>>(w_proj, wproj_h, 1152L * 1152 / 4);

    // QKV GEMM: M=16384, N=3456, K=1152 -> 64 x 27 blocks of 256x128
    gemm8<<<1728, 256, 0, stream>>>(
        x_h, wqkv_h, b_qkv, nullptr, qkv_h, 16384, 3456, 1152);

    qk_norm2<<<1024, 256, 0, stream>>>(qkv_h, q_gamma, k_gamma, k_c);
    vt_kernel<<<dim3(256, 16), 256, 0, stream>>>(qkv_h, v_t);

    attn2<<<2048, 256, 0, stream>>>(qkv_h, k_c, v_t, x_h /* ao */);

    // proj GEMM: M=16384, N=1152, K=1152 -> 64 x 9 blocks of 256x128
    gemm8<<<576, 256, 0, stream>>>(
        x_h, wproj_h, b_proj, out, nullptr, 16384, 1152, 1152);
}